// Round 6
// baseline (1170.620 us; speedup 1.0000x reference)
//
#include <hip/hip_runtime.h>
#include <math.h>

#define NV 20000
#define NE 100000
#define DD 32
#define NG 1000
#define NDEPTH 3
#define S2S 6
#define NBK 8    // src-nodes per block in k_fused
#define EPB 16   // edges per block in k_edge_t
#define CAPN 128 // max nodes of one graph staged in LDS
#define SCAN_T 256
#define SCAN_C 80  // 256*80 = 20480 >= NV

__device__ __forceinline__ float sigmoidf_(float x) { return 1.0f / (1.0f + __expf(-x)); }

// ---------------- node embedding ----------------
__global__ void k_embed_node(const float* __restrict__ node, const float* __restrict__ Wn,
                             const float* __restrict__ bn, float* __restrict__ h,
                             float* __restrict__ h0) {
    __shared__ float sW[36 * DD];
    __shared__ float sb[DD];
    __shared__ float sx[32][36];
    int tid = threadIdx.x;
    for (int i = tid; i < 36 * DD; i += 256) sW[i] = Wn[i];
    if (tid < DD) sb[tid] = bn[tid];
    int v0 = blockIdx.x * 32;
    for (int i = tid; i < 32 * 36; i += 256) sx[i / 36][i % 36] = node[(size_t)v0 * 36 + i];
    __syncthreads();
    int f = tid & 31;
    int nb = tid >> 5;
    for (int g = 0; g < 4; ++g) {
        int n = nb + 8 * g;
        float acc = sb[f];
        #pragma unroll
        for (int i = 0; i < 36; ++i) acc += sx[n][i] * sW[i * DD + f];
        float y = acc > 0.f ? acc : 0.01f * acc;
        h[(size_t)(v0 + n) * DD + f] = y;
        h0[(size_t)(v0 + n) * DD + f] = y;
    }
}

// ---------------- edge embedding ----------------
__global__ void k_embed_edge(const float* __restrict__ edge, const float* __restrict__ We,
                             const float* __restrict__ be, float* __restrict__ e_h) {
    __shared__ float sW[12 * DD];
    __shared__ float sb[DD];
    __shared__ float sx[32][12];
    int tid = threadIdx.x;
    for (int i = tid; i < 12 * DD; i += 256) sW[i] = We[i];
    if (tid < DD) sb[tid] = be[tid];
    int e0 = blockIdx.x * 32;
    for (int i = tid; i < 32 * 12; i += 256) sx[i / 12][i % 12] = edge[(size_t)e0 * 12 + i];
    __syncthreads();
    int f = tid & 31;
    int nb = tid >> 5;
    for (int g = 0; g < 4; ++g) {
        int n = nb + 8 * g;
        float acc = sb[f];
        #pragma unroll
        for (int i = 0; i < 12; ++i) acc += sx[n][i] * sW[i * DD + f];
        float y = acc > 0.f ? acc : 0.01f * acc;
        e_h[(size_t)(e0 + n) * DD + f] = y;
    }
}

// ---------------- per-layer edge hidden: t = relu(e_h @ eW1 + eb1), (E,64) ----------------
// DS-lean version: weights from LDS (conflict-free b32), e_h via uniform float4 VMEM broadcasts.
// Also zeroes agg (first 2500 blocks) so no separate memset launch.
__global__ void k_edge_t(const float* __restrict__ e_h, const float* __restrict__ eW1,
                         const float* __restrict__ eb1, float* __restrict__ t,
                         float* __restrict__ agg) {
    __shared__ float sW[DD * 64];
    __shared__ float sb[64];
    int tid = threadIdx.x;
    if (blockIdx.x < (NV * DD) / 256) agg[(size_t)blockIdx.x * 256 + tid] = 0.f;
    for (int i = tid; i < DD * 64; i += 256) sW[i] = eW1[i];
    if (tid < 64) sb[tid] = eb1[tid];
    int e0 = blockIdx.x * EPB;
    __syncthreads();
    int k = tid & 63;
    int nb = tid >> 6;                 // wave index 0..3; edge slot n = nb + 4*g
    float acc[4];
    #pragma unroll
    for (int g = 0; g < 4; ++g) acc[g] = sb[k];
    #pragma unroll
    for (int d4 = 0; d4 < 8; ++d4) {
        float4 ex[4];
        #pragma unroll
        for (int g = 0; g < 4; ++g)
            ex[g] = *(const float4*)(e_h + (size_t)(e0 + nb + 4 * g) * DD + d4 * 4);
        #pragma unroll
        for (int dd = 0; dd < 4; ++dd) {
            float w = sW[(d4 * 4 + dd) * 64 + k];   // bank = k&31: conflict-free
            #pragma unroll
            for (int g = 0; g < 4; ++g)
                acc[g] = fmaf((&ex[g].x)[dd], w, acc[g]);
        }
    }
    #pragma unroll
    for (int g = 0; g < 4; ++g)
        t[(size_t)(e0 + nb + 4 * g) * 64 + k] = fmaxf(acc[g], 0.f);
}

// ---------------- CSR build (once per launch; src is launch-constant) ----------------
__global__ void k_hist(const int* __restrict__ src, int* __restrict__ deg) {
    int e = blockIdx.x * blockDim.x + threadIdx.x;
    if (e < NE) atomicAdd(&deg[src[e]], 1);
}

__global__ void k_scan(const int* __restrict__ deg, int* __restrict__ estart, int* __restrict__ cur) {
    __shared__ int sdeg[SCAN_T * SCAN_C];
    __shared__ int spart[SCAN_T];
    int tid = threadIdx.x;
    for (int i = tid; i < SCAN_T * SCAN_C; i += SCAN_T) sdeg[i] = (i < NV) ? deg[i] : 0;
    __syncthreads();
    int base = tid * SCAN_C;
    int sum = 0;
    for (int j = 0; j < SCAN_C; ++j) sum += sdeg[base + j];
    spart[tid] = sum;
    __syncthreads();
    for (int off = 1; off < SCAN_T; off <<= 1) {
        int v = (tid >= off) ? spart[tid - off] : 0;
        __syncthreads();
        spart[tid] += v;
        __syncthreads();
    }
    int run = spart[tid] - sum;  // exclusive prefix
    for (int j = 0; j < SCAN_C; ++j) {
        int idx = base + j;
        if (idx < NV) { estart[idx] = run; cur[idx] = run; }
        run += sdeg[base + j];
    }
    if (tid == SCAN_T - 1) estart[NV] = run;
}

__global__ void k_scatter(const int* __restrict__ src, int* __restrict__ cur,
                          int* __restrict__ esorted) {
    int e = blockIdx.x * blockDim.x + threadIdx.x;
    if (e < NE) {
        int s = src[e];
        int pos = atomicAdd(&cur[s], 1);
        esorted[pos] = e | ((s & (NBK - 1)) << 24);
    }
}

// ---------------- fused: per-tile A in LDS + edge contraction + atomic scatter ----------------
// A layout: sA[n][f][64] with XOR-swizzled float4 quads (phys_q = q ^ (f&7)) so phase-2
// reads lane-f's k-row as ds_read_b128 at ~4-way conflicts instead of 64 b32 + 64 shfl.
__global__ __launch_bounds__(256) void k_fused(const float* __restrict__ h,
        const float* __restrict__ eW2, const float* __restrict__ eb2,
        const float* __restrict__ t, const int* __restrict__ dst,
        const int* __restrict__ estart, const int* __restrict__ esorted,
        float* __restrict__ agg) {
    int v0 = blockIdx.x * NBK;
    __shared__ float sA[NBK][32][64];   // 64 KB, [n][f][k-swizzled]
    __shared__ float sbb[NBK][32];
    int tid = threadIdx.x;
    int lane = tid & 63;

    // wave-register h tile: lane l holds h[v0 + (l>>3)][4*(l&7) .. +3]
    float4 hv4 = *(const float4*)(h + (size_t)(v0 + (lane >> 3)) * DD + 4 * (lane & 7));
    float ha[4] = {hv4.x, hv4.y, hv4.z, hv4.w};

    int f = tid & 31;
    int kb = tid >> 5;
    const float* wbase = eW2 + kb * 1024 + f;

    float acc[8][8];                    // [jj][n]
    #pragma unroll
    for (int jj = 0; jj < 8; ++jj)
        #pragma unroll
        for (int n = 0; n < 8; ++n) acc[jj][n] = 0.f;

    #pragma unroll
    for (int d4 = 0; d4 < 8; ++d4) {
        float hs[8][4];
        #pragma unroll
        for (int n = 0; n < 8; ++n)
            #pragma unroll
            for (int dd = 0; dd < 4; ++dd)
                hs[n][dd] = __builtin_bit_cast(float,
                    __builtin_amdgcn_readlane(__builtin_bit_cast(int, ha[dd]), n * 8 + d4));
        #pragma unroll
        for (int jj = 0; jj < 8; ++jj) {
            const float* wp = wbase + jj * 8 * 1024 + d4 * 4 * 32;
            #pragma unroll
            for (int dd = 0; dd < 4; ++dd) {
                float w = wp[dd * 32];
                #pragma unroll
                for (int n = 0; n < 8; ++n) acc[jj][n] = fmaf(hs[n][dd], w, acc[jj][n]);
            }
        }
    }
    // swizzled write: element k = kb + 8*jj -> quad q=k>>2 (phys q^(f&7)), slot k&3
    #pragma unroll
    for (int jj = 0; jj < 8; ++jj) {
        int k = kb + 8 * jj;
        int pq = (k >> 2) ^ (f & 7);
        int r = k & 3;
        #pragma unroll
        for (int n = 0; n < 8; ++n)
            sA[n][f][pq * 4 + r] = acc[jj][n];
    }

    {
        int n = tid >> 5;
        float bacc = 0.f;
        #pragma unroll
        for (int d = 0; d < DD; ++d) {
            float hvv = __shfl(ha[d & 3], n * 8 + (d >> 2), 64);
            bacc = fmaf(hvv, eb2[d * 32 + f], bacc);
        }
        sbb[n][f] = bacc;
    }
    __syncthreads();

    // edge phase: half-wave per edge; A via b128 swizzled reads, t via uniform float4 VMEM
    int e0 = estart[v0], e1 = estart[v0 + NBK];
    int hw = tid >> 5;
    for (int i = e0 + hw; i < e1; i += 8) {
        int pk = esorted[i];
        int e = pk & 0xFFFFFF;
        int ls = pk >> 24;
        const float* tp = t + (size_t)e * 64;
        const float4* arow = (const float4*)sA[ls][f];
        float m = sbb[ls][f];
        #pragma unroll
        for (int c = 0; c < 4; ++c) {
            float4 tq[4];
            #pragma unroll
            for (int q = 0; q < 4; ++q) tq[q] = *(const float4*)(tp + c * 16 + q * 4);
            #pragma unroll
            for (int q = 0; q < 4; ++q) {
                float4 av = arow[(c * 4 + q) ^ (f & 7)];
                m = fmaf(av.x, tq[q].x, m);
                m = fmaf(av.y, tq[q].y, m);
                m = fmaf(av.z, tq[q].z, m);
                m = fmaf(av.w, tq[q].w, m);
            }
        }
        atomicAdd(&agg[(size_t)dst[e] * DD + f], m);
    }
}

// ---------------- GRU (vs hidden0) + LayerNorm ----------------
// Weights transposed in LDS ([gate][f][j]: lane-j reads conflict-free, no rotation).
// Activations read directly from global as uniform float4 broadcasts (L2-hot).
__global__ void k_gru_ln(const float* __restrict__ agg, const float* __restrict__ h0,
                         const float* __restrict__ wih, const float* __restrict__ whh,
                         const float* __restrict__ bih, const float* __restrict__ bhh,
                         const float* __restrict__ lng, const float* __restrict__ lnb,
                         float* __restrict__ h) {
    __shared__ float sWT[2][3][32][32];   // [ih/hh][gate][f][j] = 24 KB
    __shared__ float sbih[96], sbhh[96], sg[DD], sb[DD];
    int tid = threadIdx.x;
    for (int i = tid; i < 3072; i += 256) {
        int g = i >> 10, j = (i >> 5) & 31, f = i & 31;
        sWT[0][g][f][j] = wih[i];
        sWT[1][g][f][j] = whh[i];
    }
    if (tid < 96) { sbih[tid] = bih[tid]; sbhh[tid] = bhh[tid]; }
    if (tid < DD) { sg[tid] = lng[tid]; sb[tid] = lnb[tid]; }
    int v0 = blockIdx.x * 32;
    __syncthreads();
    int j = tid & 31;
    int nb = tid >> 5;
    float gi0[4], gi1[4], gi2[4], gh0[4], gh1[4], gh2[4], h0j[4];
    #pragma unroll
    for (int g = 0; g < 4; ++g) {
        gi0[g] = gi1[g] = gi2[g] = gh0[g] = gh1[g] = gh2[g] = 0.f;
        h0j[g] = h0[(size_t)(v0 + nb + 8 * g) * DD + j];
    }
    #pragma unroll
    for (int f4 = 0; f4 < 8; ++f4) {
        float4 aq[4], hq[4];
        #pragma unroll
        for (int g = 0; g < 4; ++g) {
            int n = nb + 8 * g;
            float4 a = *(const float4*)(agg + (size_t)(v0 + n) * DD + f4 * 4);
            a.x = fmaxf(a.x, 0.f); a.y = fmaxf(a.y, 0.f); a.z = fmaxf(a.z, 0.f); a.w = fmaxf(a.w, 0.f);
            aq[g] = a;
            hq[g] = *(const float4*)(h0 + (size_t)(v0 + n) * DD + f4 * 4);
        }
        #pragma unroll
        for (int dd = 0; dd < 4; ++dd) {
            int f = f4 * 4 + dd;
            float wr = sWT[0][0][f][j], wz = sWT[0][1][f][j], wn = sWT[0][2][f][j];
            float ur = sWT[1][0][f][j], uz = sWT[1][1][f][j], un = sWT[1][2][f][j];
            #pragma unroll
            for (int g = 0; g < 4; ++g) {
                float a = (&aq[g].x)[dd], hh = (&hq[g].x)[dd];
                gi0[g] = fmaf(a, wr, gi0[g]);
                gi1[g] = fmaf(a, wz, gi1[g]);
                gi2[g] = fmaf(a, wn, gi2[g]);
                gh0[g] = fmaf(hh, ur, gh0[g]);
                gh1[g] = fmaf(hh, uz, gh1[g]);
                gh2[g] = fmaf(hh, un, gh2[g]);
            }
        }
    }
    float b_ir = sbih[j], b_iz = sbih[DD + j], b_in = sbih[2 * DD + j];
    float b_hr = sbhh[j], b_hz = sbhh[DD + j], b_hn = sbhh[2 * DD + j];
    float lg = sg[j], lb = sb[j];
    #pragma unroll
    for (int g = 0; g < 4; ++g) {
        float r = sigmoidf_(gi0[g] + b_ir + gh0[g] + b_hr);
        float z = sigmoidf_(gi1[g] + b_iz + gh1[g] + b_hz);
        float nn = tanhf(gi2[g] + b_in + r * (gh2[g] + b_hn));
        float hnew = (1.f - z) * nn + z * h0j[g];
        float mu = hnew;
        #pragma unroll
        for (int o = 16; o; o >>= 1) mu += __shfl_xor(mu, o, 64);
        mu *= (1.f / DD);
        float d = hnew - mu;
        float var = d * d;
        #pragma unroll
        for (int o = 16; o; o >>= 1) var += __shfl_xor(var, o, 64);
        var *= (1.f / DD);
        float inv = rsqrtf(var + 1e-5f);
        h[(size_t)(v0 + nb + 8 * g) * DD + j] = d * inv * lg + lb;
    }
}

// ---------------- graph boundaries ----------------
__global__ void k_bounds(const int* __restrict__ n2g, int* __restrict__ gstart) {
    int g = blockIdx.x * blockDim.x + threadIdx.x;
    if (g > NG) return;
    int lo = 0, hi = NV;
    while (lo < hi) {
        int mid = (lo + hi) >> 1;
        if (n2g[mid] < g) lo = mid + 1; else hi = mid;
    }
    gstart[g] = lo;
}

// ---------------- fused Set2Set + prediction MLP: 256 threads per graph ----------------
__global__ __launch_bounds__(256) void k_s2s(const float* __restrict__ h,
                      const int* __restrict__ gstart,
                      const float* __restrict__ wih, const float* __restrict__ whh,
                      const float* __restrict__ bih, const float* __restrict__ bhh,
                      const float* __restrict__ Wp1, const float* __restrict__ bp1,
                      const float* __restrict__ Wp2, const float* __restrict__ bp2,
                      float* __restrict__ attbuf, float* __restrict__ out) {
    int g = blockIdx.x, tid = threadIdx.x;
    int s = gstart[g], e = gstart[g + 1], cnt = e - s;
    bool inlds = (cnt <= CAPN);
    __shared__ float sh[CAPN * 33];
    __shared__ float qs[64], shh[32], scc[32], gbuf[128];
    __shared__ float satt[256];
    __shared__ float red[4];
    __shared__ float rpart[8][32];
    if (inlds) {
        for (int idx = tid; idx < cnt * 32; idx += 256) {
            int v = idx >> 5, f = idx & 31;
            sh[v * 33 + f] = h[(size_t)(s + v) * 32 + f];
        }
    }
    if (tid < 64) qs[tid] = 0.f;
    if (tid < 32) { shh[tid] = 0.f; scc[tid] = 0.f; }
    __syncthreads();
    for (int it = 0; it < S2S; ++it) {
        if (tid < 128) {
            float gv = bih[tid] + bhh[tid];
            const float4* w4 = (const float4*)(wih + tid * 64);
            #pragma unroll
            for (int i = 0; i < 16; ++i) {
                float4 w = w4[i];
                gv += qs[4 * i] * w.x + qs[4 * i + 1] * w.y + qs[4 * i + 2] * w.z + qs[4 * i + 3] * w.w;
            }
            const float4* u4 = (const float4*)(whh + tid * 32);
            #pragma unroll
            for (int i = 0; i < 8; ++i) {
                float4 w = u4[i];
                gv += shh[4 * i] * w.x + shh[4 * i + 1] * w.y + shh[4 * i + 2] * w.z + shh[4 * i + 3] * w.w;
            }
            gbuf[tid] = gv;
        }
        __syncthreads();
        if (tid < 32) {
            float ii = gbuf[tid], ff = gbuf[32 + tid], gg = gbuf[64 + tid], oo = gbuf[96 + tid];
            float c = sigmoidf_(ff) * scc[tid] + sigmoidf_(ii) * tanhf(gg);
            scc[tid] = c;
            float hv = sigmoidf_(oo) * tanhf(c);
            shh[tid] = hv;
            qs[tid] = hv;
        }
        __syncthreads();
        float pmax = -1e30f;
        if (inlds) {
            float a = -1e30f;
            if (tid < cnt) {
                float acc = 0.f;
                #pragma unroll
                for (int f = 0; f < 32; ++f) acc += sh[tid * 33 + f] * shh[f];
                a = acc;
            }
            satt[tid] = a;
            pmax = a;
        } else {
            for (int v = tid; v < cnt; v += 256) {
                float acc = 0.f;
                const float* hp = h + (size_t)(s + v) * 32;
                #pragma unroll
                for (int f = 0; f < 32; ++f) acc += hp[f] * shh[f];
                attbuf[s + v] = acc;
                pmax = fmaxf(pmax, acc);
            }
        }
        #pragma unroll
        for (int o = 32; o; o >>= 1) pmax = fmaxf(pmax, __shfl_xor(pmax, o, 64));
        if ((tid & 63) == 0) red[tid >> 6] = pmax;
        __syncthreads();
        float m = fmaxf(fmaxf(red[0], red[1]), fmaxf(red[2], red[3]));
        float psum = 0.f;
        if (inlds) {
            if (tid < cnt) { float exv = __expf(satt[tid] - m); satt[tid] = exv; psum = exv; }
        } else {
            for (int v = tid; v < cnt; v += 256) {
                float exv = __expf(attbuf[s + v] - m); attbuf[s + v] = exv; psum += exv;
            }
        }
        #pragma unroll
        for (int o = 32; o; o >>= 1) psum += __shfl_xor(psum, o, 64);
        __syncthreads();
        if ((tid & 63) == 0) red[tid >> 6] = psum;
        __syncthreads();
        float denom = red[0] + red[1] + red[2] + red[3];
        int f = tid & 31, vc = tid >> 5;
        float racc = 0.f;
        if (inlds) {
            for (int v = vc; v < cnt; v += 8) racc += satt[v] * sh[v * 33 + f];
        } else {
            for (int v = vc; v < cnt; v += 8) racc += attbuf[s + v] * h[(size_t)(s + v) * 32 + f];
        }
        rpart[vc][f] = racc;
        __syncthreads();
        if (tid < 32) {
            float r = 0.f;
            #pragma unroll
            for (int c2 = 0; c2 < 8; ++c2) r += rpart[c2][tid];
            qs[32 + tid] = (cnt > 0) ? (r / denom) : 0.f;
        }
        __syncthreads();
    }
    if (tid < 32) {
        float u = bp1[tid];
        #pragma unroll
        for (int p = 0; p < 64; ++p) u += qs[p] * Wp1[p * 32 + tid];
        u = fmaxf(u, 0.f);
        float pr = u * Wp2[tid];
        #pragma unroll
        for (int o = 16; o; o >>= 1) pr += __shfl_xor(pr, o, 64);
        if (tid == 0) out[g] = pr + bp2[0];
    }
}

extern "C" void kernel_launch(void* const* d_in, const int* in_sizes, int n_in,
                              void* d_out, int out_size, void* d_ws, size_t ws_size,
                              hipStream_t stream) {
    const float* node = (const float*)d_in[0];
    const float* edge = (const float*)d_in[1];
    const int*   src  = (const int*)d_in[2];
    const int*   dst  = (const int*)d_in[3];
    const int*   n2g  = (const int*)d_in[4];
    const float* Wn   = (const float*)d_in[5];
    const float* bn   = (const float*)d_in[6];
    const float* We   = (const float*)d_in[7];
    const float* be   = (const float*)d_in[8];
    const float* eW1  = (const float*)d_in[9];
    const float* eb1  = (const float*)d_in[10];
    const float* eW2  = (const float*)d_in[11];
    const float* eb2  = (const float*)d_in[12];
    const float* gwih = (const float*)d_in[13];
    const float* gwhh = (const float*)d_in[14];
    const float* gbih = (const float*)d_in[15];
    const float* gbhh = (const float*)d_in[16];
    const float* lng  = (const float*)d_in[17];
    const float* lnb  = (const float*)d_in[18];
    const float* lwih = (const float*)d_in[19];
    const float* lwhh = (const float*)d_in[20];
    const float* lbih = (const float*)d_in[21];
    const float* lbhh = (const float*)d_in[22];
    const float* Wp1  = (const float*)d_in[23];
    const float* bp1  = (const float*)d_in[24];
    const float* Wp2  = (const float*)d_in[25];
    const float* bp2  = (const float*)d_in[26];

    float* ws = (float*)d_ws;
    float* h    = ws; ws += (size_t)NV * DD;
    float* h0   = ws; ws += (size_t)NV * DD;
    float* e_h  = ws; ws += (size_t)NE * DD;
    float* t    = ws; ws += (size_t)NE * 64;
    float* agg  = ws; ws += (size_t)NV * DD;
    float* attbuf = ws; ws += NV;
    int* deg     = (int*)ws; ws += NV;
    int* cur     = (int*)ws; ws += NV;
    int* estart  = (int*)ws; ws += (NV + 1);
    int* esorted = (int*)ws; ws += NE;
    int* gstart  = (int*)ws; ws += (NG + 1);

    k_embed_node<<<(NV + 31) / 32, 256, 0, stream>>>(node, Wn, bn, h, h0);
    k_embed_edge<<<(NE + 31) / 32, 256, 0, stream>>>(edge, We, be, e_h);
    k_bounds<<<(NG + 256) / 256, 256, 0, stream>>>(n2g, gstart);

    // CSR by src (one-time; src is launch-constant)
    hipMemsetAsync(deg, 0, NV * sizeof(int), stream);
    k_hist<<<(NE + 255) / 256, 256, 0, stream>>>(src, deg);
    k_scan<<<1, SCAN_T, 0, stream>>>(deg, estart, cur);
    k_scatter<<<(NE + 255) / 256, 256, 0, stream>>>(src, cur, esorted);

    for (int l = 0; l < NDEPTH; ++l) {
        k_edge_t<<<NE / EPB, 256, 0, stream>>>(e_h, eW1 + (size_t)l * DD * 64, eb1 + l * 64, t, agg);
        k_fused<<<NV / NBK, 256, 0, stream>>>(h, eW2 + (size_t)l * 64 * 1024, eb2 + l * 1024,
                                              t, dst, estart, esorted, agg);
        k_gru_ln<<<NV / 32, 256, 0, stream>>>(agg, h0,
                                              gwih + (size_t)l * 96 * DD, gwhh + (size_t)l * 96 * DD,
                                              gbih + l * 96, gbhh + l * 96,
                                              lng + l * DD, lnb + l * DD, h);
    }

    k_s2s<<<NG, 256, 0, stream>>>(h, gstart, lwih, lwhh, lbih, lbhh, Wp1, bp1, Wp2, bp2,
                                  attbuf, (float*)d_out);
}

// Round 7
// 699.189 us; speedup vs baseline: 1.6743x; 1.6743x over previous
//
#include <hip/hip_runtime.h>
#include <math.h>

#define NV 20000
#define NE 100000
#define DD 32
#define NG 1000
#define NDEPTH 3
#define S2S 6
#define NBK 8    // src-nodes per block in k_fused
#define EPB 16   // edges per block in k_edge_t
#define CAPN 128 // max nodes of one graph staged in LDS
#define SCAN_T 256
#define SCAN_C 80  // 256*80 = 20480 >= NV

__device__ __forceinline__ float sigmoidf_(float x) { return 1.0f / (1.0f + __expf(-x)); }

// ---------------- node embedding ----------------
__global__ void k_embed_node(const float* __restrict__ node, const float* __restrict__ Wn,
                             const float* __restrict__ bn, float* __restrict__ h,
                             float* __restrict__ h0) {
    __shared__ float sW[36 * DD];
    __shared__ float sb[DD];
    __shared__ float sx[32][36];
    int tid = threadIdx.x;
    for (int i = tid; i < 36 * DD; i += 256) sW[i] = Wn[i];
    if (tid < DD) sb[tid] = bn[tid];
    int v0 = blockIdx.x * 32;
    for (int i = tid; i < 32 * 36; i += 256) sx[i / 36][i % 36] = node[(size_t)v0 * 36 + i];
    __syncthreads();
    int f = tid & 31;
    int nb = tid >> 5;
    for (int g = 0; g < 4; ++g) {
        int n = nb + 8 * g;
        float acc = sb[f];
        #pragma unroll
        for (int i = 0; i < 36; ++i) acc += sx[n][i] * sW[i * DD + f];
        float y = acc > 0.f ? acc : 0.01f * acc;
        h[(size_t)(v0 + n) * DD + f] = y;
        h0[(size_t)(v0 + n) * DD + f] = y;
    }
}

// ---------------- edge embedding ----------------
__global__ void k_embed_edge(const float* __restrict__ edge, const float* __restrict__ We,
                             const float* __restrict__ be, float* __restrict__ e_h) {
    __shared__ float sW[12 * DD];
    __shared__ float sb[DD];
    __shared__ float sx[32][12];
    int tid = threadIdx.x;
    for (int i = tid; i < 12 * DD; i += 256) sW[i] = We[i];
    if (tid < DD) sb[tid] = be[tid];
    int e0 = blockIdx.x * 32;
    for (int i = tid; i < 32 * 12; i += 256) sx[i / 12][i % 12] = edge[(size_t)e0 * 12 + i];
    __syncthreads();
    int f = tid & 31;
    int nb = tid >> 5;
    for (int g = 0; g < 4; ++g) {
        int n = nb + 8 * g;
        float acc = sb[f];
        #pragma unroll
        for (int i = 0; i < 12; ++i) acc += sx[n][i] * sW[i * DD + f];
        float y = acc > 0.f ? acc : 0.01f * acc;
        e_h[(size_t)(e0 + n) * DD + f] = y;
    }
}

// ---------------- per-layer edge hidden: t = relu(e_h @ eW1 + eb1), (E,64) ----------------
// Weights in LDS (conflict-free b32), e_h via uniform float4 VMEM broadcasts.
// Also zeroes agg (first 2500 blocks).
__global__ void k_edge_t(const float* __restrict__ e_h, const float* __restrict__ eW1,
                         const float* __restrict__ eb1, float* __restrict__ t,
                         float* __restrict__ agg) {
    __shared__ float sW[DD * 64];
    __shared__ float sb[64];
    int tid = threadIdx.x;
    if (blockIdx.x < (NV * DD) / 256) agg[(size_t)blockIdx.x * 256 + tid] = 0.f;
    for (int i = tid; i < DD * 64; i += 256) sW[i] = eW1[i];
    if (tid < 64) sb[tid] = eb1[tid];
    int e0 = blockIdx.x * EPB;
    __syncthreads();
    int k = tid & 63;
    int nb = tid >> 6;                 // wave index 0..3; edge slot n = nb + 4*g
    float acc[4];
    #pragma unroll
    for (int g = 0; g < 4; ++g) acc[g] = sb[k];
    #pragma unroll
    for (int d4 = 0; d4 < 8; ++d4) {
        float4 ex[4];
        #pragma unroll
        for (int g = 0; g < 4; ++g)
            ex[g] = *(const float4*)(e_h + (size_t)(e0 + nb + 4 * g) * DD + d4 * 4);
        #pragma unroll
        for (int dd = 0; dd < 4; ++dd) {
            float w = sW[(d4 * 4 + dd) * 64 + k];   // bank = k&31: conflict-free
            #pragma unroll
            for (int g = 0; g < 4; ++g)
                acc[g] = fmaf((&ex[g].x)[dd], w, acc[g]);
        }
    }
    #pragma unroll
    for (int g = 0; g < 4; ++g)
        t[(size_t)(e0 + nb + 4 * g) * 64 + k] = fmaxf(acc[g], 0.f);
}

// ---------------- CSR build (once per launch; src is launch-constant) ----------------
__global__ void k_hist(const int* __restrict__ src, int* __restrict__ deg) {
    int e = blockIdx.x * blockDim.x + threadIdx.x;
    if (e < NE) atomicAdd(&deg[src[e]], 1);
}

__global__ void k_scan(const int* __restrict__ deg, int* __restrict__ estart, int* __restrict__ cur) {
    __shared__ int sdeg[SCAN_T * SCAN_C];
    __shared__ int spart[SCAN_T];
    int tid = threadIdx.x;
    for (int i = tid; i < SCAN_T * SCAN_C; i += SCAN_T) sdeg[i] = (i < NV) ? deg[i] : 0;
    __syncthreads();
    int base = tid * SCAN_C;
    int sum = 0;
    for (int j = 0; j < SCAN_C; ++j) sum += sdeg[base + j];
    spart[tid] = sum;
    __syncthreads();
    for (int off = 1; off < SCAN_T; off <<= 1) {
        int v = (tid >= off) ? spart[tid - off] : 0;
        __syncthreads();
        spart[tid] += v;
        __syncthreads();
    }
    int run = spart[tid] - sum;  // exclusive prefix
    for (int j = 0; j < SCAN_C; ++j) {
        int idx = base + j;
        if (idx < NV) { estart[idx] = run; cur[idx] = run; }
        run += sdeg[base + j];
    }
    if (tid == SCAN_T - 1) estart[NV] = run;
}

__global__ void k_scatter(const int* __restrict__ src, int* __restrict__ cur,
                          int* __restrict__ esorted) {
    int e = blockIdx.x * blockDim.x + threadIdx.x;
    if (e < NE) {
        int s = src[e];
        int pos = atomicAdd(&cur[s], 1);
        esorted[pos] = e;
    }
}

// ---------------- fused: per-tile A in LDS + per-node A-in-registers edge phase ----------------
__global__ __launch_bounds__(256, 2) void k_fused(const float* __restrict__ h,
        const float* __restrict__ eW2, const float* __restrict__ eb2,
        const float* __restrict__ t, const int* __restrict__ dst,
        const int* __restrict__ estart, const int* __restrict__ esorted,
        float* __restrict__ agg) {
    int v0 = blockIdx.x * NBK;
    __shared__ float sA[NBK][64][32];   // 64 KB, [n][k][f]
    __shared__ float sbb[NBK][32];
    int tid = threadIdx.x;
    int lane = tid & 63;

    // wave-register h tile: lane l holds h[v0 + (l>>3)][4*(l&7) .. +3]
    float4 hv4 = *(const float4*)(h + (size_t)(v0 + (lane >> 3)) * DD + 4 * (lane & 7));
    float ha[4] = {hv4.x, hv4.y, hv4.z, hv4.w};

    int f = tid & 31;
    int kb = tid >> 5;
    const float* wbase = eW2 + kb * 1024 + f;

    float acc[8][8];                    // [jj][n]
    #pragma unroll
    for (int jj = 0; jj < 8; ++jj)
        #pragma unroll
        for (int n = 0; n < 8; ++n) acc[jj][n] = 0.f;

    #pragma unroll
    for (int d4 = 0; d4 < 8; ++d4) {
        float hs[8][4];
        #pragma unroll
        for (int n = 0; n < 8; ++n)
            #pragma unroll
            for (int dd = 0; dd < 4; ++dd)
                hs[n][dd] = __builtin_bit_cast(float,
                    __builtin_amdgcn_readlane(__builtin_bit_cast(int, ha[dd]), n * 8 + d4));
        #pragma unroll
        for (int jj = 0; jj < 8; ++jj) {
            const float* wp = wbase + jj * 8 * 1024 + d4 * 4 * 32;
            #pragma unroll
            for (int dd = 0; dd < 4; ++dd) {
                float w = wp[dd * 32];
                #pragma unroll
                for (int n = 0; n < 8; ++n) acc[jj][n] = fmaf(hs[n][dd], w, acc[jj][n]);
            }
        }
    }
    #pragma unroll
    for (int jj = 0; jj < 8; ++jj)
        #pragma unroll
        for (int n = 0; n < 8; ++n)
            sA[n][kb + 8 * jj][f] = acc[jj][n];

    {
        int n = tid >> 5;
        float bacc = 0.f;
        #pragma unroll
        for (int d = 0; d < DD; ++d) {
            float hvv = __shfl(ha[d & 3], n * 8 + (d >> 2), 64);
            bacc = fmaf(hvv, eb2[d * 32 + f], bacc);
        }
        sbb[n][f] = bacc;
    }
    __syncthreads();

    // edge phase: one wave per src-node (2 nodes/wave sequentially), A in registers.
    // lane (f, hf): Areg[q] = A[n][2q+hf][f]; per edge: 32 bpermute + 32 FMA + 1 swap.
    int wid = tid >> 6;
    int hf = lane >> 5;
    for (int n2 = 0; n2 < 2; ++n2) {
        int n = wid * 2 + n2;
        float Areg[32];
        #pragma unroll
        for (int q = 0; q < 32; ++q)
            Areg[q] = sA[n][2 * q + hf][f];   // 2 lanes/bank, different addr: free
        float bbv = sbb[n][f];
        int e0 = estart[v0 + n], e1 = estart[v0 + n + 1];
        for (int i = e0; i < e1; ++i) {
            int e = esorted[i];
            float tv = t[(size_t)e * 64 + lane];   // coalesced 256B
            int dn = dst[e];
            float m = 0.f;
            #pragma unroll
            for (int q = 0; q < 32; ++q)
                m = fmaf(__shfl(tv, 2 * q + hf, 64), Areg[q], m);
            m += __shfl_xor(m, 32, 64);
            if (lane < 32) atomicAdd(&agg[(size_t)dn * DD + f], m + bbv);
        }
    }
}

// ---------------- GRU (vs hidden0) + LayerNorm ----------------
// 8 nodes/block, 2500 blocks. Weights transposed in LDS with +1 pad (conflict-free
// staging AND reads); activations in registers via VMEM.
__global__ __launch_bounds__(256, 2) void k_gru_ln(const float* __restrict__ agg,
                         const float* __restrict__ h0,
                         const float* __restrict__ wih, const float* __restrict__ whh,
                         const float* __restrict__ bih, const float* __restrict__ bhh,
                         const float* __restrict__ lng, const float* __restrict__ lnb,
                         float* __restrict__ h) {
    __shared__ float sWT[2][3][32][33];   // [ih/hh][gate][f][j], j-dim padded
    __shared__ float sbih[96], sbhh[96], sg[DD], sb[DD];
    int tid = threadIdx.x;
    for (int i = tid; i < 3072; i += 256) {
        int g = i >> 10, j = (i >> 5) & 31, f = i & 31;   // wih[i] = W[g*32+j][f]
        sWT[0][g][f][j] = wih[i];    // addr stride 33 across lanes: conflict-free
        sWT[1][g][f][j] = whh[i];
    }
    if (tid < 96) { sbih[tid] = bih[tid]; sbhh[tid] = bhh[tid]; }
    if (tid < DD) { sg[tid] = lng[tid]; sb[tid] = lnb[tid]; }
    int v0 = blockIdx.x * 8;
    __syncthreads();
    int j = tid & 31;
    int n = v0 + (tid >> 5);
    // activations in registers (uniform/coalesced VMEM, L2-hot)
    float4 aq[8], hq[8];
    #pragma unroll
    for (int f4 = 0; f4 < 8; ++f4) {
        float4 a = *(const float4*)(agg + (size_t)n * DD + f4 * 4);
        a.x = fmaxf(a.x, 0.f); a.y = fmaxf(a.y, 0.f); a.z = fmaxf(a.z, 0.f); a.w = fmaxf(a.w, 0.f);
        aq[f4] = a;
        hq[f4] = *(const float4*)(h0 + (size_t)n * DD + f4 * 4);
    }
    float h0j = h0[(size_t)n * DD + j];
    float gi0 = 0.f, gi1 = 0.f, gi2 = 0.f, gh0 = 0.f, gh1 = 0.f, gh2 = 0.f;
    #pragma unroll
    for (int f4 = 0; f4 < 8; ++f4) {
        #pragma unroll
        for (int dd = 0; dd < 4; ++dd) {
            int f = f4 * 4 + dd;
            float a = (&aq[f4].x)[dd], hh = (&hq[f4].x)[dd];
            gi0 = fmaf(a, sWT[0][0][f][j], gi0);
            gi1 = fmaf(a, sWT[0][1][f][j], gi1);
            gi2 = fmaf(a, sWT[0][2][f][j], gi2);
            gh0 = fmaf(hh, sWT[1][0][f][j], gh0);
            gh1 = fmaf(hh, sWT[1][1][f][j], gh1);
            gh2 = fmaf(hh, sWT[1][2][f][j], gh2);
        }
    }
    float r = sigmoidf_(gi0 + sbih[j] + gh0 + sbhh[j]);
    float z = sigmoidf_(gi1 + sbih[DD + j] + gh1 + sbhh[DD + j]);
    float nn = tanhf(gi2 + sbih[2 * DD + j] + r * (gh2 + sbhh[2 * DD + j]));
    float hnew = (1.f - z) * nn + z * h0j;
    float mu = hnew;
    #pragma unroll
    for (int o = 16; o; o >>= 1) mu += __shfl_xor(mu, o, 64);
    mu *= (1.f / DD);
    float d = hnew - mu;
    float var = d * d;
    #pragma unroll
    for (int o = 16; o; o >>= 1) var += __shfl_xor(var, o, 64);
    var *= (1.f / DD);
    float inv = rsqrtf(var + 1e-5f);
    h[(size_t)n * DD + j] = d * inv * sg[j] + sb[j];
}

// ---------------- graph boundaries ----------------
__global__ void k_bounds(const int* __restrict__ n2g, int* __restrict__ gstart) {
    int g = blockIdx.x * blockDim.x + threadIdx.x;
    if (g > NG) return;
    int lo = 0, hi = NV;
    while (lo < hi) {
        int mid = (lo + hi) >> 1;
        if (n2g[mid] < g) lo = mid + 1; else hi = mid;
    }
    gstart[g] = lo;
}

// ---------------- fused Set2Set + prediction MLP: 256 threads per graph ----------------
__global__ __launch_bounds__(256) void k_s2s(const float* __restrict__ h,
                      const int* __restrict__ gstart,
                      const float* __restrict__ wih, const float* __restrict__ whh,
                      const float* __restrict__ bih, const float* __restrict__ bhh,
                      const float* __restrict__ Wp1, const float* __restrict__ bp1,
                      const float* __restrict__ Wp2, const float* __restrict__ bp2,
                      float* __restrict__ attbuf, float* __restrict__ out) {
    int g = blockIdx.x, tid = threadIdx.x;
    int s = gstart[g], e = gstart[g + 1], cnt = e - s;
    bool inlds = (cnt <= CAPN);
    __shared__ float sh[CAPN * 33];
    __shared__ float qs[64], shh[32], scc[32], gbuf[128];
    __shared__ float satt[256];
    __shared__ float red[4];
    __shared__ float rpart[8][32];
    if (inlds) {
        for (int idx = tid; idx < cnt * 32; idx += 256) {
            int v = idx >> 5, f = idx & 31;
            sh[v * 33 + f] = h[(size_t)(s + v) * 32 + f];
        }
    }
    if (tid < 64) qs[tid] = 0.f;
    if (tid < 32) { shh[tid] = 0.f; scc[tid] = 0.f; }
    __syncthreads();
    for (int it = 0; it < S2S; ++it) {
        if (tid < 128) {
            float gv = bih[tid] + bhh[tid];
            const float4* w4 = (const float4*)(wih + tid * 64);
            #pragma unroll
            for (int i = 0; i < 16; ++i) {
                float4 w = w4[i];
                gv += qs[4 * i] * w.x + qs[4 * i + 1] * w.y + qs[4 * i + 2] * w.z + qs[4 * i + 3] * w.w;
            }
            const float4* u4 = (const float4*)(whh + tid * 32);
            #pragma unroll
            for (int i = 0; i < 8; ++i) {
                float4 w = u4[i];
                gv += shh[4 * i] * w.x + shh[4 * i + 1] * w.y + shh[4 * i + 2] * w.z + shh[4 * i + 3] * w.w;
            }
            gbuf[tid] = gv;
        }
        __syncthreads();
        if (tid < 32) {
            float ii = gbuf[tid], ff = gbuf[32 + tid], gg = gbuf[64 + tid], oo = gbuf[96 + tid];
            float c = sigmoidf_(ff) * scc[tid] + sigmoidf_(ii) * tanhf(gg);
            scc[tid] = c;
            float hv = sigmoidf_(oo) * tanhf(c);
            shh[tid] = hv;
            qs[tid] = hv;
        }
        __syncthreads();
        float pmax = -1e30f;
        if (inlds) {
            float a = -1e30f;
            if (tid < cnt) {
                float acc = 0.f;
                #pragma unroll
                for (int f = 0; f < 32; ++f) acc += sh[tid * 33 + f] * shh[f];
                a = acc;
            }
            satt[tid] = a;
            pmax = a;
        } else {
            for (int v = tid; v < cnt; v += 256) {
                float acc = 0.f;
                const float* hp = h + (size_t)(s + v) * 32;
                #pragma unroll
                for (int f = 0; f < 32; ++f) acc += hp[f] * shh[f];
                attbuf[s + v] = acc;
                pmax = fmaxf(pmax, acc);
            }
        }
        #pragma unroll
        for (int o = 32; o; o >>= 1) pmax = fmaxf(pmax, __shfl_xor(pmax, o, 64));
        if ((tid & 63) == 0) red[tid >> 6] = pmax;
        __syncthreads();
        float m = fmaxf(fmaxf(red[0], red[1]), fmaxf(red[2], red[3]));
        float psum = 0.f;
        if (inlds) {
            if (tid < cnt) { float exv = __expf(satt[tid] - m); satt[tid] = exv; psum = exv; }
        } else {
            for (int v = tid; v < cnt; v += 256) {
                float exv = __expf(attbuf[s + v] - m); attbuf[s + v] = exv; psum += exv;
            }
        }
        #pragma unroll
        for (int o = 32; o; o >>= 1) psum += __shfl_xor(psum, o, 64);
        __syncthreads();
        if ((tid & 63) == 0) red[tid >> 6] = psum;
        __syncthreads();
        float denom = red[0] + red[1] + red[2] + red[3];
        int f = tid & 31, vc = tid >> 5;
        float racc = 0.f;
        if (inlds) {
            for (int v = vc; v < cnt; v += 8) racc += satt[v] * sh[v * 33 + f];
        } else {
            for (int v = vc; v < cnt; v += 8) racc += attbuf[s + v] * h[(size_t)(s + v) * 32 + f];
        }
        rpart[vc][f] = racc;
        __syncthreads();
        if (tid < 32) {
            float r = 0.f;
            #pragma unroll
            for (int c2 = 0; c2 < 8; ++c2) r += rpart[c2][tid];
            qs[32 + tid] = (cnt > 0) ? (r / denom) : 0.f;
        }
        __syncthreads();
    }
    if (tid < 32) {
        float u = bp1[tid];
        #pragma unroll
        for (int p = 0; p < 64; ++p) u += qs[p] * Wp1[p * 32 + tid];
        u = fmaxf(u, 0.f);
        float pr = u * Wp2[tid];
        #pragma unroll
        for (int o = 16; o; o >>= 1) pr += __shfl_xor(pr, o, 64);
        if (tid == 0) out[g] = pr + bp2[0];
    }
}

extern "C" void kernel_launch(void* const* d_in, const int* in_sizes, int n_in,
                              void* d_out, int out_size, void* d_ws, size_t ws_size,
                              hipStream_t stream) {
    const float* node = (const float*)d_in[0];
    const float* edge = (const float*)d_in[1];
    const int*   src  = (const int*)d_in[2];
    const int*   dst  = (const int*)d_in[3];
    const int*   n2g  = (const int*)d_in[4];
    const float* Wn   = (const float*)d_in[5];
    const float* bn   = (const float*)d_in[6];
    const float* We   = (const float*)d_in[7];
    const float* be   = (const float*)d_in[8];
    const float* eW1  = (const float*)d_in[9];
    const float* eb1  = (const float*)d_in[10];
    const float* eW2  = (const float*)d_in[11];
    const float* eb2  = (const float*)d_in[12];
    const float* gwih = (const float*)d_in[13];
    const float* gwhh = (const float*)d_in[14];
    const float* gbih = (const float*)d_in[15];
    const float* gbhh = (const float*)d_in[16];
    const float* lng  = (const float*)d_in[17];
    const float* lnb  = (const float*)d_in[18];
    const float* lwih = (const float*)d_in[19];
    const float* lwhh = (const float*)d_in[20];
    const float* lbih = (const float*)d_in[21];
    const float* lbhh = (const float*)d_in[22];
    const float* Wp1  = (const float*)d_in[23];
    const float* bp1  = (const float*)d_in[24];
    const float* Wp2  = (const float*)d_in[25];
    const float* bp2  = (const float*)d_in[26];

    float* ws = (float*)d_ws;
    float* h    = ws; ws += (size_t)NV * DD;
    float* h0   = ws; ws += (size_t)NV * DD;
    float* e_h  = ws; ws += (size_t)NE * DD;
    float* t    = ws; ws += (size_t)NE * 64;
    float* agg  = ws; ws += (size_t)NV * DD;
    float* attbuf = ws; ws += NV;
    int* deg     = (int*)ws; ws += NV;
    int* cur     = (int*)ws; ws += NV;
    int* estart  = (int*)ws; ws += (NV + 1);
    int* esorted = (int*)ws; ws += NE;
    int* gstart  = (int*)ws; ws += (NG + 1);

    k_embed_node<<<(NV + 31) / 32, 256, 0, stream>>>(node, Wn, bn, h, h0);
    k_embed_edge<<<(NE + 31) / 32, 256, 0, stream>>>(edge, We, be, e_h);
    k_bounds<<<(NG + 256) / 256, 256, 0, stream>>>(n2g, gstart);

    // CSR by src (one-time; src is launch-constant)
    hipMemsetAsync(deg, 0, NV * sizeof(int), stream);
    k_hist<<<(NE + 255) / 256, 256, 0, stream>>>(src, deg);
    k_scan<<<1, SCAN_T, 0, stream>>>(deg, estart, cur);
    k_scatter<<<(NE + 255) / 256, 256, 0, stream>>>(src, cur, esorted);

    for (int l = 0; l < NDEPTH; ++l) {
        k_edge_t<<<NE / EPB, 256, 0, stream>>>(e_h, eW1 + (size_t)l * DD * 64, eb1 + l * 64, t, agg);
        k_fused<<<NV / NBK, 256, 0, stream>>>(h, eW2 + (size_t)l * 64 * 1024, eb2 + l * 1024,
                                              t, dst, estart, esorted, agg);
        k_gru_ln<<<NV / 8, 256, 0, stream>>>(agg, h0,
                                             gwih + (size_t)l * 96 * DD, gwhh + (size_t)l * 96 * DD,
                                             gbih + l * 96, gbhh + l * 96,
                                             lng + l * DD, lnb + l * DD, h);
    }

    k_s2s<<<NG, 256, 0, stream>>>(h, gstart, lwih, lwhh, lbih, lbhh, Wp1, bp1, Wp2, bp2,
                                  attbuf, (float*)d_out);
}